// Round 1
// 429.265 us; speedup vs baseline: 1.0080x; 1.0080x over previous
//
#include <hip/hip_runtime.h>
#include <hip/hip_bf16.h>
#include <math.h>

// ---------- types ----------
typedef __attribute__((ext_vector_type(8))) short s8vec;     // 8 x bf16 bits (4 VGPRs)
typedef __attribute__((ext_vector_type(16))) float f32x16;   // 32x32 MFMA C/D
typedef __attribute__((ext_vector_type(4))) unsigned short us4;

__device__ __forceinline__ unsigned short f2bf(float f) {
  unsigned u = __float_as_uint(f);
  u = (u + 0x7fffu + ((u >> 16) & 1u)) >> 16;   // RNE
  return (unsigned short)u;
}
__device__ __forceinline__ float bf2f(unsigned short u) {
  return __uint_as_float(((unsigned)u) << 16);
}

// fast gelu: t * sigmoid(1.5957691t + 0.07135481t^3); |err vs erf-gelu| < 3e-3
__device__ __forceinline__ float fast_gelu(float t) {
  float t2 = t * t;
  float u = t * (1.59576912f + 0.07135481f * t2);
  float e = __expf(-u);
  return t * __frcp_rn(1.0f + e);
}

// async global->LDS, 16B per lane. LDS dest = wave-uniform base + lane*16.
__device__ __forceinline__ void async_ld16(const unsigned short* g, unsigned short* l) {
  __builtin_amdgcn_global_load_lds(
      (__attribute__((address_space(1))) void*)g,
      (__attribute__((address_space(3))) void*)l, 16, 0, 0);
}

// ============================================================================
// 8-phase 256xBN NT GEMM: C[M,N] = A[M,K] * Bt[N,K]^T        (BN = 256 or 128)
//
// Schedule (T2+T3+T4+T5): BK=64, 8 waves (2M x 4N), per-wave 128 x BN/4 via
// 32x32x16 bf16 MFMA. Double-buffered LDS (128 KiB @BN=256). Each K-tile is 4
// phases (one 32-row M-quadrant each):
//   { ds_read frags | issue prefetch stripes } ; s_barrier ; lgkmcnt(0) ;
//   sched_barrier(0) ; setprio(1) ; 8(or 4) MFMA ; setprio(0) ; s_barrier
// Staging unit = 8 KiB "stripe" (one global_load_lds per thread).  Pipeline
// (derived + region-deadness checked against the 2-barrier phase structure):
//   tile T phase0: stage A-s2,s3 of T+1 (other buf; regions dead since T-1)
//   tile T phase1: stage B-lo     of T+2 (this buf; B dead after phase0)
//   tile T phase2: stage B-hi     of T+2
//   tile T phase3: stage A-s0,s1  of T+2 (dead after phases 0,1)
// Boundary: s_waitcnt vmcnt(6 /4 for BN=128)  (= stripes of T+2 in flight),
// never 0 in steady state -> loads span barriers; vmcnt(0) only in the tail.
//
// LDS swizzle (kept from round 0, measured 0 bank-conflict cycles): 16B chunk
// c of row r stored at c ^ (r&7) ^ ((r>>3)&3); global source pre-swizzled so
// global_load_lds stays linear; reads apply the same XOR.
// C/D: col=lane&31, row=(reg&3)+8*(reg>>2)+4*(lane>>5).
// EPI: 0 = out_bf16 = acc*scale; 1 = out_f32 = acc+res;
//      2 = out_bf16 = gelu(acc+bias); 3 = out_f32 = acc+bias+res
// ============================================================================

#define STA(q, tk, bofs) async_ld16(srcA[q] + ((size_t)(tk) << 6), &As[(bofs) + ldsA[q]])
#define STB(j, tk, bofs) async_ld16(srcB[j] + ((size_t)(tk) << 6), &Bs[(bofs) + ldsB[j]])

#define ARD(Q)                                                              \
  _Pragma("unroll") for (int s = 0; s < 4; ++s)                             \
      af[s] = *(const s8vec*)&As[aB + aoff + (Q)*2048 + pc[s]];

#define MFMA_PH(Q)                                                          \
  __builtin_amdgcn_s_barrier();                                             \
  asm volatile("s_waitcnt lgkmcnt(0)" ::: "memory");                        \
  __builtin_amdgcn_sched_barrier(0);                                        \
  __builtin_amdgcn_s_setprio(1);                                            \
  _Pragma("unroll") for (int s = 0; s < 4; ++s) {                           \
    _Pragma("unroll") for (int nf = 0; nf < NF; ++nf)                       \
      acc[Q][nf] = __builtin_amdgcn_mfma_f32_32x32x16_bf16(                 \
          af[s], b[nf][s], acc[Q][nf], 0, 0, 0);                            \
  }                                                                         \
  __builtin_amdgcn_s_setprio(0);

template <int BN, int EPI>
__global__ __launch_bounds__(512, 2) void gemm_nt8(
    const unsigned short* __restrict__ A, const unsigned short* __restrict__ B,
    float* __restrict__ outF, unsigned short* __restrict__ outB,
    const float* __restrict__ bias, const float* __restrict__ res,
    int M, int N, int K,
    long long bA, long long bB, long long bO, long long bR, float scale)
{
  static_assert(BN == 256 || BN == 128, "BN must be 256 or 128");
  constexpr int NB = BN / 64;      // B stage stripes per K-tile (4 or 2)
  constexpr int NF = BN / 128;     // N-frags per wave (2 or 1)
  constexpr int WN = BN / 4;       // wave N extent (64 or 32)
  constexpr int ABUF = 256 * 64;   // elements per A buffer (32 KiB)
  constexpr int BBUF = BN * 64;

  __shared__ __align__(16) unsigned short As[2 * ABUF];
  __shared__ __align__(16) unsigned short Bs[2 * BBUF];

  (void)M;
  const int tid = threadIdx.x;
  const int w = tid >> 6;          // wave 0..7
  const int l = tid & 63;
  const int z = blockIdx.z;
  A += (size_t)z * bA;
  B += (size_t)z * bB;
  const size_t tileM = (size_t)blockIdx.y * 256;
  const size_t tileN = (size_t)blockIdx.x * BN;

  // ---- staging source pointers (global pre-swizzled, LDS linear) ----
  const int sub = w & 3, half = w >> 2;
  const unsigned short* srcA[4];
  int ldsA[4];
#pragma unroll
  for (int q = 0; q < 4; ++q) {
    const int rb = q * 32 + sub * 8 + half * 128;      // stripe q: rows {32q..}+{128+32q..}
    const int r = rb + (l >> 3);
    const int c = (l & 7) ^ (r & 7) ^ ((r >> 3) & 3);
    srcA[q] = A + (tileM + r) * (size_t)K + (c << 3);
    ldsA[q] = rb * 64;
  }
  const unsigned short* srcB[NB];
  int ldsB[NB];
#pragma unroll
  for (int j = 0; j < NB; ++j) {
    const int rb = j * 64 + w * 8;
    const int r = rb + (l >> 3);
    const int c = (l & 7) ^ (r & 7) ^ ((r >> 3) & 3);
    srcB[j] = B + (tileN + r) * (size_t)K + (c << 3);
    ldsB[j] = rb * 64;
  }

  // ---- compute-side fragment addressing ----
  const int wm = half;             // wave M origin / 128
  const int wn = sub;              // wave N origin / WN
  const int fr = l & 31;
  const int fq = l >> 5;
  const int swz = (l & 7) ^ ((l >> 3) & 3);            // = f(row) for row=base+fr, base%32==0
  int pc[4];
#pragma unroll
  for (int s = 0; s < 4; ++s) pc[s] = ((((s << 1) + fq) ^ swz) << 3);
  const int aoff = (wm * 128 + fr) * 64;
  int boff[NF];
#pragma unroll
  for (int nf = 0; nf < NF; ++nf) boff[nf] = (wn * WN + nf * 32 + fr) * 64;

  f32x16 acc[4][NF] = {};
  const int NT = K >> 6;           // K-tiles (>=16 for all call sites, even)

  // ---- prologue: tile0 full (oldest), tile1 B + A-s0,s1 ----
  STA(0, 0, 0); STA(1, 0, 0); STA(2, 0, 0); STA(3, 0, 0);
#pragma unroll
  for (int j = 0; j < NB; ++j) STB(j, 0, 0);
#pragma unroll
  for (int j = 0; j < NB; ++j) STB(j, 1, BBUF);
  STA(0, 1, ABUF); STA(1, 1, ABUF);
  if constexpr (BN == 256) asm volatile("s_waitcnt vmcnt(6)" ::: "memory");
  else                     asm volatile("s_waitcnt vmcnt(4)" ::: "memory");
  __builtin_amdgcn_s_barrier();

  auto tile = [&](int t, int bf) {
    const int aB = bf * ABUF;
    const int bBo = bf * BBUF;
    const int oaB = (bf ^ 1) * ABUF;
    const bool g1 = (t + 1 < NT), g2 = (t + 2 < NT);
    s8vec b[NF][4];
    s8vec af[4];

    // -- phase 0: quadrant 0 + all B frags; stage A-s2,s3 of t+1 --
    ARD(0);
#pragma unroll
    for (int nf = 0; nf < NF; ++nf)
#pragma unroll
      for (int s = 0; s < 4; ++s)
        b[nf][s] = *(const s8vec*)&Bs[bBo + boff[nf] + pc[s]];
    if (g1) { STA(2, t + 1, oaB); STA(3, t + 1, oaB); }
    MFMA_PH(0);
    __builtin_amdgcn_s_barrier();

    // -- phase 1: quadrant 1; stage B-lo of t+2 (B of tile t dead after ph0) --
    ARD(1);
    if (g2) {
      if constexpr (BN == 256) { STB(0, t + 2, bBo); STB(1, t + 2, bBo); }
      else                     { STB(0, t + 2, bBo); }
    }
    MFMA_PH(1);
    __builtin_amdgcn_s_barrier();

    // -- phase 2: quadrant 2; stage B-hi of t+2 --
    ARD(2);
    if (g2) {
      if constexpr (BN == 256) { STB(2, t + 2, bBo); STB(3, t + 2, bBo); }
      else                     { STB(1, t + 2, bBo); }
    }
    MFMA_PH(2);
    __builtin_amdgcn_s_barrier();

    // -- phase 3: quadrant 3; stage A-s0,s1 of t+2 (dead after ph0,ph1) --
    ARD(3);
    if (g2) { STA(0, t + 2, aB); STA(1, t + 2, aB); }
    MFMA_PH(3);
    // boundary: counted vmcnt (drains through tile t+1's last stripe)
    if (g2) {
      if constexpr (BN == 256) asm volatile("s_waitcnt vmcnt(6)" ::: "memory");
      else                     asm volatile("s_waitcnt vmcnt(4)" ::: "memory");
    } else {
      asm volatile("s_waitcnt vmcnt(0)" ::: "memory");
    }
    __builtin_amdgcn_s_barrier();
  };

  for (int t = 0; t < NT; t += 2) { tile(t, 0); tile(t + 1, 1); }

  // ---- epilogue.  C/D: col = lane&31, row = (reg&3)+8*(reg>>2)+4*(lane>>5) ----
  float* oF = outF + (size_t)z * bO;
  unsigned short* oB = outB + (size_t)z * bO;
  const float* rs = res + (size_t)z * bR;

  float bcol[NF];
  if (EPI >= 2) {
#pragma unroll
    for (int nf = 0; nf < NF; ++nf) bcol[nf] = bias[tileN + wn * WN + nf * 32 + fr];
  }

#pragma unroll
  for (int mf = 0; mf < 4; ++mf) {
#pragma unroll
    for (int r = 0; r < 16; ++r) {
      const size_t row = tileM + wm * 128 + (mf << 5) + (r & 3) + ((r >> 2) << 3) + (fq << 2);
      const size_t rb = row * (size_t)N;
#pragma unroll
      for (int nf = 0; nf < NF; ++nf) {
        const size_t col = tileN + wn * WN + (nf << 5) + fr;
        const float v = acc[mf][nf][r];
        if (EPI == 0) {
          oB[rb + col] = f2bf(v * scale);
        } else if (EPI == 1) {
          oF[rb + col] = v + rs[rb + col];
        } else if (EPI == 2) {
          oB[rb + col] = f2bf(fast_gelu(v + bcol[nf]));
        } else {
          oF[rb + col] = v + bcol[nf] + rs[rb + col];
        }
      }
    }
  }
}

// ---------- LayerNorm over rows of 1024 fp32 -> bf16 ----------
__global__ __launch_bounds__(256) void ln_row(
    const float* __restrict__ x, const float* __restrict__ gamma,
    const float* __restrict__ beta, unsigned short* __restrict__ out)
{
  const int row = blockIdx.x;
  const float4* xr = (const float4*)(x + (size_t)row * 1024);
  const int tid = threadIdx.x;
  float4 v = xr[tid];
  float s = v.x + v.y + v.z + v.w;
  float q = v.x * v.x + v.y * v.y + v.z * v.z + v.w * v.w;
#pragma unroll
  for (int off = 32; off > 0; off >>= 1) {
    s += __shfl_down(s, off);
    q += __shfl_down(q, off);
  }
  __shared__ float rs_[4], rq_[4];
  const int w = tid >> 6, l = tid & 63;
  if (l == 0) { rs_[w] = s; rq_[w] = q; }
  __syncthreads();
  s = rs_[0] + rs_[1] + rs_[2] + rs_[3];
  q = rq_[0] + rq_[1] + rq_[2] + rq_[3];
  const float mu = s * (1.0f / 1024.0f);
  const float var = q * (1.0f / 1024.0f) - mu * mu;
  const float rstd = rsqrtf(var + 1e-5f);
  const float4 g = ((const float4*)gamma)[tid];
  const float4 b = ((const float4*)beta)[tid];
  us4 o;
  o.x = f2bf((v.x - mu) * rstd * g.x + b.x);
  o.y = f2bf((v.y - mu) * rstd * g.y + b.y);
  o.z = f2bf((v.z - mu) * rstd * g.z + b.z);
  o.w = f2bf((v.w - mu) * rstd * g.w + b.w);
  ((us4*)(out + (size_t)row * 1024))[tid] = o;
}

// ---------- softmax over rows of 2048 bf16 -> bf16 ----------
__global__ __launch_bounds__(256) void softmax_row(
    const unsigned short* __restrict__ sc, unsigned short* __restrict__ pr)
{
  const int row = blockIdx.x;
  const s8vec* s8 = (const s8vec*)(sc + (size_t)row * 2048);
  const int tid = threadIdx.x;
  s8vec a = s8[tid];                 // 8 bf16
  float x[8];
#pragma unroll
  for (int i = 0; i < 8; ++i) x[i] = bf2f((unsigned short)a[i]);
  float mx = x[0];
#pragma unroll
  for (int i = 1; i < 8; ++i) mx = fmaxf(mx, x[i]);
#pragma unroll
  for (int off = 32; off > 0; off >>= 1) mx = fmaxf(mx, __shfl_down(mx, off));
  __shared__ float red[4];
  const int w = tid >> 6, l = tid & 63;
  if (l == 0) red[w] = mx;
  __syncthreads();
  mx = fmaxf(fmaxf(red[0], red[1]), fmaxf(red[2], red[3]));
  __syncthreads();
  float e[8], s = 0.f;
#pragma unroll
  for (int i = 0; i < 8; ++i) { e[i] = __expf(x[i] - mx); s += e[i]; }
#pragma unroll
  for (int off = 32; off > 0; off >>= 1) s += __shfl_down(s, off);
  if (l == 0) red[w] = s;
  __syncthreads();
  s = red[0] + red[1] + red[2] + red[3];
  const float inv = 1.0f / s;
  s8vec o;
#pragma unroll
  for (int i = 0; i < 8; ++i) o[i] = (short)f2bf(e[i] * inv);
  ((s8vec*)(pr + (size_t)row * 2048))[tid] = o;
}

// ---------- transpose + convert to bf16: in[R,C] -> out[C,R] ----------
template <bool BF16IN>
__global__ __launch_bounds__(256) void transpose_conv(
    const void* __restrict__ in_, unsigned short* __restrict__ out,
    int R, int C, long long bIn, long long bOut)
{
  __shared__ float tile[32][33];
  const int z = blockIdx.z;
  const int tx = threadIdx.x, ty = threadIdx.y;   // block (32,8)
  const int c0 = blockIdx.x * 32, r0 = blockIdx.y * 32;
  if (BF16IN) {
    const unsigned short* in = (const unsigned short*)in_ + (size_t)z * bIn;
    for (int i = ty; i < 32; i += 8)
      tile[i][tx] = bf2f(in[(size_t)(r0 + i) * C + c0 + tx]);
  } else {
    const float* in = (const float*)in_ + (size_t)z * bIn;
    for (int i = ty; i < 32; i += 8)
      tile[i][tx] = in[(size_t)(r0 + i) * C + c0 + tx];
  }
  __syncthreads();
  unsigned short* o = out + (size_t)z * bOut;
  for (int i = ty; i < 32; i += 8)
    o[(size_t)(c0 + i) * R + r0 + tx] = f2bf(tile[tx][i]);
}

// ---------- launch ----------
extern "C" void kernel_launch(void* const* d_in, const int* in_sizes, int n_in,
                              void* d_out, int out_size, void* d_ws, size_t ws_size,
                              hipStream_t stream)
{
  (void)in_sizes; (void)n_in; (void)out_size; (void)ws_size;
  const float* src = (const float*)d_in[0];
  const float* g1  = (const float*)d_in[1];
  const float* be1 = (const float*)d_in[2];
  const float* g2  = (const float*)d_in[3];
  const float* be2 = (const float*)d_in[4];
  const float* w1  = (const float*)d_in[5];
  const float* b1  = (const float*)d_in[6];
  const float* w2  = (const float*)d_in[7];
  const float* b2  = (const float*)d_in[8];
  float* out = (float*)d_out;

  // workspace layout (bytes). Peak = 184,549,376.
  char* ws = (char*)d_ws;
  const size_t SZ_NORMX  = (size_t)8192 * 1024 * 2;     // 16 MiB
  const size_t SZ_SCORES = (size_t)4 * 2048 * 2048 * 4; // 64 MiB region (scores bf16 uses half; hbuf uses all)
  const size_t SZ_PROBS  = (size_t)4 * 2048 * 2048 * 2; // 32 MiB
  const size_t SZ_X      = (size_t)8192 * 1024 * 4;     // 32 MiB
  const size_t SZ_W1T    = (size_t)1024 * 4096 * 2;     // 8 MiB

  unsigned short* normx  = (unsigned short*)(ws);
  unsigned short* normxT = (unsigned short*)(ws + SZ_NORMX);
  unsigned short* scores = (unsigned short*)(ws + 2 * SZ_NORMX);
  unsigned short* probs  = (unsigned short*)(ws + 2 * SZ_NORMX + SZ_SCORES);
  float*          xbuf   = (float*)(ws + 2 * SZ_NORMX + SZ_SCORES + SZ_PROBS);
  unsigned short* w1t    = (unsigned short*)(ws + 2 * SZ_NORMX + SZ_SCORES + SZ_PROBS + SZ_X);
  unsigned short* w2t    = (unsigned short*)(ws + 2 * SZ_NORMX + SZ_SCORES + SZ_PROBS + SZ_X + SZ_W1T);
  unsigned short* normx2 = normx;                       // reuse (dead after attn)
  unsigned short* hbuf   = scores;                      // reuse (dead after softmax)

  const dim3 tb(32, 8);
  // weights fp32 -> bf16 transposed (every call; ws is re-poisoned)
  transpose_conv<false><<<dim3(128, 32, 1), tb, 0, stream>>>(w1, w1t, 1024, 4096, 0, 0);
  transpose_conv<false><<<dim3(32, 128, 1), tb, 0, stream>>>(w2, w2t, 4096, 1024, 0, 0);

  // LN1
  ln_row<<<8192, 256, 0, stream>>>(src, g1, be1, normx);
  // normx^T per batch (for PV as NT)
  transpose_conv<true><<<dim3(32, 64, 4), tb, 0, stream>>>(
      normx, normxT, 2048, 1024, (long long)2048 * 1024, (long long)1024 * 2048);

  // scores = bf16(normx . normx^T / 32)
  gemm_nt8<256, 0><<<dim3(8, 8, 4), 512, 0, stream>>>(
      normx, normx, nullptr, scores, nullptr, nullptr,
      2048, 2048, 1024,
      (long long)2048 * 1024, (long long)2048 * 1024, (long long)2048 * 2048, 0, 0.03125f);

  // softmax rows (bf16 in/out)
  softmax_row<<<8192, 256, 0, stream>>>(scores, probs);

  // x = probs . normx + src
  gemm_nt8<128, 1><<<dim3(8, 8, 4), 512, 0, stream>>>(
      probs, normxT, xbuf, nullptr, nullptr, src,
      2048, 1024, 2048,
      (long long)2048 * 2048, (long long)1024 * 2048, (long long)2048 * 1024,
      (long long)2048 * 1024, 1.0f);

  // LN2
  ln_row<<<8192, 256, 0, stream>>>(xbuf, g2, be2, normx2);

  // h = gelu(normx2 . w1 + b1)
  gemm_nt8<256, 2><<<dim3(16, 32, 1), 512, 0, stream>>>(
      normx2, w1t, nullptr, hbuf, b1, nullptr,
      8192, 4096, 1024, 0, 0, 0, 0, 1.0f);

  // out = h . w2 + b2 + x
  gemm_nt8<128, 3><<<dim3(8, 32, 1), 512, 0, stream>>>(
      hbuf, w2t, out, nullptr, b2, xbuf,
      8192, 1024, 4096, 0, 0, 0, 0, 1.0f);
}

// Round 2
// 402.695 us; speedup vs baseline: 1.0745x; 1.0660x over previous
//
#include <hip/hip_runtime.h>
#include <hip/hip_bf16.h>
#include <math.h>

// ---------- types ----------
typedef __attribute__((ext_vector_type(8))) short s8vec;     // 8 x bf16 bits (4 VGPRs)
typedef __attribute__((ext_vector_type(16))) float f32x16;   // 32x32 MFMA C/D
typedef __attribute__((ext_vector_type(4))) unsigned short us4;

__device__ __forceinline__ unsigned short f2bf(float f) {
  unsigned u = __float_as_uint(f);
  u = (u + 0x7fffu + ((u >> 16) & 1u)) >> 16;   // RNE
  return (unsigned short)u;
}
__device__ __forceinline__ float bf2f(unsigned short u) {
  return __uint_as_float(((unsigned)u) << 16);
}

// fast gelu: t * sigmoid(1.5957691t + 0.07135481t^3); |err vs erf-gelu| < 3e-3
__device__ __forceinline__ float fast_gelu(float t) {
  float t2 = t * t;
  float u = t * (1.59576912f + 0.07135481f * t2);
  float e = __expf(-u);
  return t * __frcp_rn(1.0f + e);
}

// async global->LDS, 16B per lane. LDS dest = wave-uniform base + lane*16.
__device__ __forceinline__ void async_ld16(const unsigned short* g, unsigned short* l) {
  __builtin_amdgcn_global_load_lds(
      (__attribute__((address_space(1))) void*)g,
      (__attribute__((address_space(3))) void*)l, 16, 0, 0);
}

// ============================================================================
// 256xBN NT GEMM: C[M,N] = A[M,K] * Bt[N,K]^T              (BN = 256 or 128)
//
// T1: XCD-aware bijective block remap (nwg%8==0, gx/gy pow2 at all sites):
// XCD k gets a contiguous chunk of logical tiles (x-fastest), so N-blocks
// sharing an A-panel co-reside on one XCD's L2 instead of 8 copies across
// all XCDs (round-1 counters: 276 MB FETCH vs ~100 ideal on the BN=128 site).
//
// Schedule (T2+T3+T4+T5): BK=64, 8 waves (2M x 4N), 32x32x16 bf16 MFMA,
// double-buffered LDS.  BN=256: 4 phases/K-tile (one 32-row M-quadrant, 8
// MFMA each).  BN=128: 2 merged phases/K-tile (two quadrants, 8 MFMA each)
// — same MFMA density per barrier-pair as BN=256; round-1's 4-MFMA phases
// were barrier-overhead-bound.
// Phase = { ds_read frags | issue prefetch stripes } ; s_barrier ; lgkmcnt(0);
// sched_barrier(0) ; setprio(1) ; 8 MFMA ; setprio(0) ; s_barrier.
// Counted vmcnt at tile boundary only (6 for BN=256, 4 for BN=128), never 0
// in steady state.  Staging ledger (region last read >=1 barrier earlier):
//   BN=256: ph0 A-s2,s3(t+1,other) | ph1 B01(t+2) | ph2 B23(t+2) | ph3 A-s0,s1(t+2)
//   BN=128: phA A-s2,s3(t+1,other) | phB B01(t+2)+A-s0,s1(t+2)
//
// LDS swizzle (0 measured conflict cycles): 16B chunk c of row r at
// c ^ (r&7) ^ ((r>>3)&3); global source pre-swizzled, LDS linear.
// C/D: col=lane&31, row=(reg&3)+8*(reg>>2)+4*(lane>>5).
// EPI: 0 = out_bf16 = acc*scale; 1 = out_f32 = acc+res;
//      2 = out_bf16 = gelu(acc+bias); 3 = out_f32 = acc+bias+res
// ============================================================================

#define STA(q, tk, bofs) async_ld16(srcA[q] + ((size_t)(tk) << 6), &As[(bofs) + ldsA[q]])
#define STB(j, tk, bofs) async_ld16(srcB[j] + ((size_t)(tk) << 6), &Bs[(bofs) + ldsB[j]])

#define PH_SYNC_PRE()                                                       \
  __builtin_amdgcn_s_barrier();                                             \
  asm volatile("s_waitcnt lgkmcnt(0)" ::: "memory");                        \
  __builtin_amdgcn_sched_barrier(0);                                        \
  __builtin_amdgcn_s_setprio(1)

#define PH_SYNC_POST()                                                      \
  __builtin_amdgcn_s_setprio(0);                                            \
  __builtin_amdgcn_s_barrier()

template <int BN, int EPI>
__global__ __launch_bounds__(512, 2) void gemm_nt8(
    const unsigned short* __restrict__ A, const unsigned short* __restrict__ B,
    float* __restrict__ outF, unsigned short* __restrict__ outB,
    const float* __restrict__ bias, const float* __restrict__ res,
    int M, int N, int K,
    long long bA, long long bB, long long bO, long long bR, float scale)
{
  static_assert(BN == 256 || BN == 128, "BN must be 256 or 128");
  constexpr int NB = BN / 64;      // B stage stripes per K-tile (4 or 2)
  constexpr int NF = BN / 128;     // N-frags per wave (2 or 1)
  constexpr int WN = BN / 4;       // wave N extent (64 or 32)
  constexpr int ABUF = 256 * 64;   // elements per A buffer (32 KiB)
  constexpr int BBUF = BN * 64;

  __shared__ __align__(16) unsigned short As[2 * ABUF];
  __shared__ __align__(16) unsigned short Bs[2 * BBUF];

  (void)M;
  const int tid = threadIdx.x;
  const int w = tid >> 6;          // wave 0..7
  const int l = tid & 63;

  // ---- T1: XCD-aware bijective remap (nwg % 8 == 0, gx/gy pow2) ----
  const unsigned gx = gridDim.x, gy = gridDim.y;
  unsigned lin = blockIdx.x + gx * (blockIdx.y + gy * blockIdx.z);
  const unsigned nwg = gx * gy * gridDim.z;
  lin = (lin & 7u) * (nwg >> 3) + (lin >> 3);
  const unsigned bx = lin & (gx - 1u);
  const unsigned tmp = lin >> __builtin_ctz(gx);
  const unsigned by = tmp & (gy - 1u);
  const unsigned bz = tmp >> __builtin_ctz(gy);

  const int z = (int)bz;
  A += (size_t)z * bA;
  B += (size_t)z * bB;
  const size_t tileM = (size_t)by * 256;
  const size_t tileN = (size_t)bx * BN;

  // ---- staging source pointers (global pre-swizzled, LDS linear) ----
  const int sub = w & 3, half = w >> 2;
  const unsigned short* srcA[4];
  int ldsA[4];
#pragma unroll
  for (int q = 0; q < 4; ++q) {
    const int rb = q * 32 + sub * 8 + half * 128;      // stripe q: rows {32q..}+{128+32q..}
    const int r = rb + (l >> 3);
    const int c = (l & 7) ^ (r & 7) ^ ((r >> 3) & 3);
    srcA[q] = A + (tileM + r) * (size_t)K + (c << 3);
    ldsA[q] = rb * 64;
  }
  const unsigned short* srcB[NB];
  int ldsB[NB];
#pragma unroll
  for (int j = 0; j < NB; ++j) {
    const int rb = j * 64 + w * 8;
    const int r = rb + (l >> 3);
    const int c = (l & 7) ^ (r & 7) ^ ((r >> 3) & 3);
    srcB[j] = B + (tileN + r) * (size_t)K + (c << 3);
    ldsB[j] = rb * 64;
  }

  // ---- compute-side fragment addressing ----
  const int wm = half;             // wave M origin / 128
  const int wn = sub;              // wave N origin / WN
  const int fr = l & 31;
  const int fq = l >> 5;
  const int swz = (l & 7) ^ ((l >> 3) & 3);            // = f(row) for row=base+fr, base%32==0
  int pc[4];
#pragma unroll
  for (int s = 0; s < 4; ++s) pc[s] = ((((s << 1) + fq) ^ swz) << 3);
  const int aoff = (wm * 128 + fr) * 64;
  int boff[NF];
#pragma unroll
  for (int nf = 0; nf < NF; ++nf) boff[nf] = (wn * WN + nf * 32 + fr) * 64;

  f32x16 acc[4][NF] = {};
  const int NT = K >> 6;           // K-tiles (>=16 and even at all call sites)

  if constexpr (BN == 256) {
    // ---- prologue: t0 full (oldest 8), then t1 B (4) + A-s0,s1 (2) ----
    STA(0, 0, 0); STA(1, 0, 0); STA(2, 0, 0); STA(3, 0, 0);
#pragma unroll
    for (int j = 0; j < 4; ++j) STB(j, 0, 0);
#pragma unroll
    for (int j = 0; j < 4; ++j) STB(j, 1, BBUF);
    STA(0, 1, ABUF); STA(1, 1, ABUF);
    asm volatile("s_waitcnt vmcnt(6)" ::: "memory");
    __builtin_amdgcn_s_barrier();

    auto tile = [&](int t, int bf) {
      const int aB = bf * ABUF, bBo = bf * BBUF, oaB = (bf ^ 1) * ABUF;
      const bool g1 = (t + 1 < NT), g2 = (t + 2 < NT);
      s8vec b[2][4];
      s8vec af[4];

      // -- phase 0: quadrant 0 + all B frags; stage A-s2,s3 of t+1 --
#pragma unroll
      for (int s = 0; s < 4; ++s) af[s] = *(const s8vec*)&As[aB + aoff + 0 * 2048 + pc[s]];
#pragma unroll
      for (int nf = 0; nf < 2; ++nf)
#pragma unroll
        for (int s = 0; s < 4; ++s)
          b[nf][s] = *(const s8vec*)&Bs[bBo + boff[nf] + pc[s]];
      if (g1) { STA(2, t + 1, oaB); STA(3, t + 1, oaB); }
      PH_SYNC_PRE();
#pragma unroll
      for (int s = 0; s < 4; ++s)
#pragma unroll
        for (int nf = 0; nf < 2; ++nf)
          acc[0][nf] = __builtin_amdgcn_mfma_f32_32x32x16_bf16(af[s], b[nf][s], acc[0][nf], 0, 0, 0);
      PH_SYNC_POST();

      // -- phase 1: quadrant 1; stage B-lo of t+2 --
#pragma unroll
      for (int s = 0; s < 4; ++s) af[s] = *(const s8vec*)&As[aB + aoff + 1 * 2048 + pc[s]];
      if (g2) { STB(0, t + 2, bBo); STB(1, t + 2, bBo); }
      PH_SYNC_PRE();
#pragma unroll
      for (int s = 0; s < 4; ++s)
#pragma unroll
        for (int nf = 0; nf < 2; ++nf)
          acc[1][nf] = __builtin_amdgcn_mfma_f32_32x32x16_bf16(af[s], b[nf][s], acc[1][nf], 0, 0, 0);
      PH_SYNC_POST();

      // -- phase 2: quadrant 2; stage B-hi of t+2 --
#pragma unroll
      for (int s = 0; s < 4; ++s) af[s] = *(const s8vec*)&As[aB + aoff + 2 * 2048 + pc[s]];
      if (g2) { STB(2, t + 2, bBo); STB(3, t + 2, bBo); }
      PH_SYNC_PRE();
#pragma unroll
      for (int s = 0; s < 4; ++s)
#pragma unroll
        for (int nf = 0; nf < 2; ++nf)
          acc[2][nf] = __builtin_amdgcn_mfma_f32_32x32x16_bf16(af[s], b[nf][s], acc[2][nf], 0, 0, 0);
      PH_SYNC_POST();

      // -- phase 3: quadrant 3; stage A-s0,s1 of t+2; boundary vmcnt --
#pragma unroll
      for (int s = 0; s < 4; ++s) af[s] = *(const s8vec*)&As[aB + aoff + 3 * 2048 + pc[s]];
      if (g2) { STA(0, t + 2, aB); STA(1, t + 2, aB); }
      PH_SYNC_PRE();
#pragma unroll
      for (int s = 0; s < 4; ++s)
#pragma unroll
        for (int nf = 0; nf < 2; ++nf)
          acc[3][nf] = __builtin_amdgcn_mfma_f32_32x32x16_bf16(af[s], b[nf][s], acc[3][nf], 0, 0, 0);
      __builtin_amdgcn_s_setprio(0);
      if (g2) asm volatile("s_waitcnt vmcnt(6)" ::: "memory");
      else    asm volatile("s_waitcnt vmcnt(0)" ::: "memory");
      __builtin_amdgcn_s_barrier();
    };

    for (int t = 0; t < NT; t += 2) { tile(t, 0); tile(t + 1, 1); }
  } else {
    // ---- prologue: t0 full (oldest 6), then t1 B (2) + A-s0,s1 (2) ----
    STA(0, 0, 0); STA(1, 0, 0); STA(2, 0, 0); STA(3, 0, 0);
    STB(0, 0, 0); STB(1, 0, 0);
    STB(0, 1, BBUF); STB(1, 1, BBUF);
    STA(0, 1, ABUF); STA(1, 1, ABUF);
    asm volatile("s_waitcnt vmcnt(4)" ::: "memory");
    __builtin_amdgcn_s_barrier();

    auto tile = [&](int t, int bf) {
      const int aB = bf * ABUF, bBo = bf * BBUF, oaB = (bf ^ 1) * ABUF;
      const bool g1 = (t + 1 < NT), g2 = (t + 2 < NT);
      s8vec b[4], a0[4], a1[4];

      // -- phase A: B frags + quadrants 0,1; stage A-s2,s3 of t+1 (other buf) --
#pragma unroll
      for (int s = 0; s < 4; ++s) {
        b[s]  = *(const s8vec*)&Bs[bBo + boff[0] + pc[s]];
        a0[s] = *(const s8vec*)&As[aB + aoff + 0 * 2048 + pc[s]];
        a1[s] = *(const s8vec*)&As[aB + aoff + 1 * 2048 + pc[s]];
      }
      if (g1) { STA(2, t + 1, oaB); STA(3, t + 1, oaB); }
      PH_SYNC_PRE();
#pragma unroll
      for (int s = 0; s < 4; ++s) {
        acc[0][0] = __builtin_amdgcn_mfma_f32_32x32x16_bf16(a0[s], b[s], acc[0][0], 0, 0, 0);
        acc[1][0] = __builtin_amdgcn_mfma_f32_32x32x16_bf16(a1[s], b[s], acc[1][0], 0, 0, 0);
      }
      PH_SYNC_POST();

      // -- phase B: quadrants 2,3; stage B01(t+2) + A-s0,s1(t+2) (this buf) --
#pragma unroll
      for (int s = 0; s < 4; ++s) {
        a0[s] = *(const s8vec*)&As[aB + aoff + 2 * 2048 + pc[s]];
        a1[s] = *(const s8vec*)&As[aB + aoff + 3 * 2048 + pc[s]];
      }
      if (g2) { STB(0, t + 2, bBo); STB(1, t + 2, bBo); STA(0, t + 2, aB); STA(1, t + 2, aB); }
      PH_SYNC_PRE();
#pragma unroll
      for (int s = 0; s < 4; ++s) {
        acc[2][0] = __builtin_amdgcn_mfma_f32_32x32x16_bf16(a0[s], b[s], acc[2][0], 0, 0, 0);
        acc[3][0] = __builtin_amdgcn_mfma_f32_32x32x16_bf16(a1[s], b[s], acc[3][0], 0, 0, 0);
      }
      __builtin_amdgcn_s_setprio(0);
      // boundary: 4 from t-1.phB + 2 from t.phA drain (= tile t+1 complete);
      // the 4 stripes of t+2 stay in flight.
      if (g2) asm volatile("s_waitcnt vmcnt(4)" ::: "memory");
      else    asm volatile("s_waitcnt vmcnt(0)" ::: "memory");
      __builtin_amdgcn_s_barrier();
    };

    for (int t = 0; t < NT; t += 2) { tile(t, 0); tile(t + 1, 1); }
  }

  // ---- epilogue.  C/D: col = lane&31, row = (reg&3)+8*(reg>>2)+4*(lane>>5) ----
  float* oF = outF + (size_t)z * bO;
  unsigned short* oB = outB + (size_t)z * bO;
  const float* rs = res + (size_t)z * bR;

  float bcol[NF];
  if (EPI >= 2) {
#pragma unroll
    for (int nf = 0; nf < NF; ++nf) bcol[nf] = bias[tileN + wn * WN + nf * 32 + fr];
  }

#pragma unroll
  for (int mf = 0; mf < 4; ++mf) {
#pragma unroll
    for (int r = 0; r < 16; ++r) {
      const size_t row = tileM + wm * 128 + (mf << 5) + (r & 3) + ((r >> 2) << 3) + (fq << 2);
      const size_t rb = row * (size_t)N;
#pragma unroll
      for (int nf = 0; nf < NF; ++nf) {
        const size_t col = tileN + wn * WN + (nf << 5) + fr;
        const float v = acc[mf][nf][r];
        if (EPI == 0) {
          oB[rb + col] = f2bf(v * scale);
        } else if (EPI == 1) {
          oF[rb + col] = v + rs[rb + col];
        } else if (EPI == 2) {
          oB[rb + col] = f2bf(fast_gelu(v + bcol[nf]));
        } else {
          oF[rb + col] = v + bcol[nf] + rs[rb + col];
        }
      }
    }
  }
}

// ---------- LayerNorm over rows of 1024 fp32 -> bf16 ----------
__global__ __launch_bounds__(256) void ln_row(
    const float* __restrict__ x, const float* __restrict__ gamma,
    const float* __restrict__ beta, unsigned short* __restrict__ out)
{
  const int row = blockIdx.x;
  const float4* xr = (const float4*)(x + (size_t)row * 1024);
  const int tid = threadIdx.x;
  float4 v = xr[tid];
  float s = v.x + v.y + v.z + v.w;
  float q = v.x * v.x + v.y * v.y + v.z * v.z + v.w * v.w;
#pragma unroll
  for (int off = 32; off > 0; off >>= 1) {
    s += __shfl_down(s, off);
    q += __shfl_down(q, off);
  }
  __shared__ float rs_[4], rq_[4];
  const int w = tid >> 6, l = tid & 63;
  if (l == 0) { rs_[w] = s; rq_[w] = q; }
  __syncthreads();
  s = rs_[0] + rs_[1] + rs_[2] + rs_[3];
  q = rq_[0] + rq_[1] + rq_[2] + rq_[3];
  const float mu = s * (1.0f / 1024.0f);
  const float var = q * (1.0f / 1024.0f) - mu * mu;
  const float rstd = rsqrtf(var + 1e-5f);
  const float4 g = ((const float4*)gamma)[tid];
  const float4 b = ((const float4*)beta)[tid];
  us4 o;
  o.x = f2bf((v.x - mu) * rstd * g.x + b.x);
  o.y = f2bf((v.y - mu) * rstd * g.y + b.y);
  o.z = f2bf((v.z - mu) * rstd * g.z + b.z);
  o.w = f2bf((v.w - mu) * rstd * g.w + b.w);
  ((us4*)(out + (size_t)row * 1024))[tid] = o;
}

// ---------- softmax over rows of 2048 bf16 -> bf16 ----------
__global__ __launch_bounds__(256) void softmax_row(
    const unsigned short* __restrict__ sc, unsigned short* __restrict__ pr)
{
  const int row = blockIdx.x;
  const s8vec* s8 = (const s8vec*)(sc + (size_t)row * 2048);
  const int tid = threadIdx.x;
  s8vec a = s8[tid];                 // 8 bf16
  float x[8];
#pragma unroll
  for (int i = 0; i < 8; ++i) x[i] = bf2f((unsigned short)a[i]);
  float mx = x[0];
#pragma unroll
  for (int i = 1; i < 8; ++i) mx = fmaxf(mx, x[i]);
#pragma unroll
  for (int off = 32; off > 0; off >>= 1) mx = fmaxf(mx, __shfl_down(mx, off));
  __shared__ float red[4];
  const int w = tid >> 6, l = tid & 63;
  if (l == 0) red[w] = mx;
  __syncthreads();
  mx = fmaxf(fmaxf(red[0], red[1]), fmaxf(red[2], red[3]));
  __syncthreads();
  float e[8], s = 0.f;
#pragma unroll
  for (int i = 0; i < 8; ++i) { e[i] = __expf(x[i] - mx); s += e[i]; }
#pragma unroll
  for (int off = 32; off > 0; off >>= 1) s += __shfl_down(s, off);
  if (l == 0) red[w] = s;
  __syncthreads();
  s = red[0] + red[1] + red[2] + red[3];
  const float inv = 1.0f / s;
  s8vec o;
#pragma unroll
  for (int i = 0; i < 8; ++i) o[i] = (short)f2bf(e[i] * inv);
  ((s8vec*)(pr + (size_t)row * 2048))[tid] = o;
}

// ---------- transpose + convert to bf16: in[R,C] -> out[C,R] ----------
template <bool BF16IN>
__global__ __launch_bounds__(256) void transpose_conv(
    const void* __restrict__ in_, unsigned short* __restrict__ out,
    int R, int C, long long bIn, long long bOut)
{
  __shared__ float tile[32][33];
  const int z = blockIdx.z;
  const int tx = threadIdx.x, ty = threadIdx.y;   // block (32,8)
  const int c0 = blockIdx.x * 32, r0 = blockIdx.y * 32;
  if (BF16IN) {
    const unsigned short* in = (const unsigned short*)in_ + (size_t)z * bIn;
    for (int i = ty; i < 32; i += 8)
      tile[i][tx] = bf2f(in[(size_t)(r0 + i) * C + c0 + tx]);
  } else {
    const float* in = (const float*)in_ + (size_t)z * bIn;
    for (int i = ty; i < 32; i += 8)
      tile[i][tx] = in[(size_t)(r0 + i) * C + c0 + tx];
  }
  __syncthreads();
  unsigned short* o = out + (size_t)z * bOut;
  for (int i = ty; i < 32; i += 8)
    o[(size_t)(c0 + i) * R + r0 + tx] = f2bf(tile[tx][i]);
}

// ---------- launch ----------
extern "C" void kernel_launch(void* const* d_in, const int* in_sizes, int n_in,
                              void* d_out, int out_size, void* d_ws, size_t ws_size,
                              hipStream_t stream)
{
  (void)in_sizes; (void)n_in; (void)out_size; (void)ws_size;
  const float* src = (const float*)d_in[0];
  const float* g1  = (const float*)d_in[1];
  const float* be1 = (const float*)d_in[2];
  const float* g2  = (const float*)d_in[3];
  const float* be2 = (const float*)d_in[4];
  const float* w1  = (const float*)d_in[5];
  const float* b1  = (const float*)d_in[6];
  const float* w2  = (const float*)d_in[7];
  const float* b2  = (const float*)d_in[8];
  float* out = (float*)d_out;

  // workspace layout (bytes). Peak = 184,549,376.
  char* ws = (char*)d_ws;
  const size_t SZ_NORMX  = (size_t)8192 * 1024 * 2;     // 16 MiB
  const size_t SZ_SCORES = (size_t)4 * 2048 * 2048 * 4; // 64 MiB region (scores bf16 uses half; hbuf uses all)
  const size_t SZ_PROBS  = (size_t)4 * 2048 * 2048 * 2; // 32 MiB
  const size_t SZ_X      = (size_t)8192 * 1024 * 4;     // 32 MiB
  const size_t SZ_W1T    = (size_t)1024 * 4096 * 2;     // 8 MiB

  unsigned short* normx  = (unsigned short*)(ws);
  unsigned short* normxT = (unsigned short*)(ws + SZ_NORMX);
  unsigned short* scores = (unsigned short*)(ws + 2 * SZ_NORMX);
  unsigned short* probs  = (unsigned short*)(ws + 2 * SZ_NORMX + SZ_SCORES);
  float*          xbuf   = (float*)(ws + 2 * SZ_NORMX + SZ_SCORES + SZ_PROBS);
  unsigned short* w1t    = (unsigned short*)(ws + 2 * SZ_NORMX + SZ_SCORES + SZ_PROBS + SZ_X);
  unsigned short* w2t    = (unsigned short*)(ws + 2 * SZ_NORMX + SZ_SCORES + SZ_PROBS + SZ_X + SZ_W1T);
  unsigned short* normx2 = normx;                       // reuse (dead after attn)
  unsigned short* hbuf   = scores;                      // reuse (dead after softmax)

  const dim3 tb(32, 8);
  // weights fp32 -> bf16 transposed (every call; ws is re-poisoned)
  transpose_conv<false><<<dim3(128, 32, 1), tb, 0, stream>>>(w1, w1t, 1024, 4096, 0, 0);
  transpose_conv<false><<<dim3(32, 128, 1), tb, 0, stream>>>(w2, w2t, 4096, 1024, 0, 0);

  // LN1
  ln_row<<<8192, 256, 0, stream>>>(src, g1, be1, normx);
  // normx^T per batch (for PV as NT)
  transpose_conv<true><<<dim3(32, 64, 4), tb, 0, stream>>>(
      normx, normxT, 2048, 1024, (long long)2048 * 1024, (long long)1024 * 2048);

  // scores = bf16(normx . normx^T / 32)
  gemm_nt8<256, 0><<<dim3(8, 8, 4), 512, 0, stream>>>(
      normx, normx, nullptr, scores, nullptr, nullptr,
      2048, 2048, 1024,
      (long long)2048 * 1024, (long long)2048 * 1024, (long long)2048 * 2048, 0, 0.03125f);

  // softmax rows (bf16 in/out)
  softmax_row<<<8192, 256, 0, stream>>>(scores, probs);

  // x = probs . normx + src
  gemm_nt8<128, 1><<<dim3(8, 8, 4), 512, 0, stream>>>(
      probs, normxT, xbuf, nullptr, nullptr, src,
      2048, 1024, 2048,
      (long long)2048 * 2048, (long long)1024 * 2048, (long long)2048 * 1024,
      (long long)2048 * 1024, 1.0f);

  // LN2
  ln_row<<<8192, 256, 0, stream>>>(xbuf, g2, be2, normx2);

  // h = gelu(normx2 . w1 + b1)
  gemm_nt8<256, 2><<<dim3(16, 32, 1), 512, 0, stream>>>(
      normx2, w1t, nullptr, hbuf, b1, nullptr,
      8192, 4096, 1024, 0, 0, 0, 0, 1.0f);

  // out = h . w2 + b2 + x
  gemm_nt8<128, 3><<<dim3(8, 32, 1), 512, 0, stream>>>(
      hbuf, w2t, out, nullptr, b2, xbuf,
      8192, 1024, 4096, 0, 0, 0, 0, 1.0f);
}

// Round 3
// 399.078 us; speedup vs baseline: 1.0842x; 1.0091x over previous
//
#include <hip/hip_runtime.h>
#include <hip/hip_bf16.h>
#include <math.h>

// ---------- types ----------
typedef __attribute__((ext_vector_type(8))) short s8vec;     // 8 x bf16 bits (4 VGPRs)
typedef __attribute__((ext_vector_type(16))) float f32x16;   // 32x32 MFMA C/D
typedef __attribute__((ext_vector_type(4))) unsigned short us4;

__device__ __forceinline__ unsigned short f2bf(float f) {
  unsigned u = __float_as_uint(f);
  u = (u + 0x7fffu + ((u >> 16) & 1u)) >> 16;   // RNE
  return (unsigned short)u;
}
__device__ __forceinline__ float bf2f(unsigned short u) {
  return __uint_as_float(((unsigned)u) << 16);
}

// fast gelu: t * sigmoid(1.5957691t + 0.07135481t^3); |err vs erf-gelu| < 3e-3
__device__ __forceinline__ float fast_gelu(float t) {
  float t2 = t * t;
  float u = t * (1.59576912f + 0.07135481f * t2);
  float e = __expf(-u);
  return t * __frcp_rn(1.0f + e);
}

// async global->LDS, 16B per lane. LDS dest = wave-uniform base + lane*16.
__device__ __forceinline__ void async_ld16(const unsigned short* g, unsigned short* l) {
  __builtin_amdgcn_global_load_lds(
      (__attribute__((address_space(1))) void*)g,
      (__attribute__((address_space(3))) void*)l, 16, 0, 0);
}

// ============================================================================
// 256xBN NT GEMM: C[M,N] = A[M,K] * Bt[N,K]^T              (BN = 256 or 128)
//
// T1 XCD remap + T2 swizzle + T3/T4 counted-sync + T5 setprio, PLUS in-tile
// operand READ-AHEAD: ds_reads for phase p+1 are issued in window p and drain
// under phase p's MFMA segment; MFMA(p) waits a counted lgkmcnt (DS returns
// in-order per wave) so only the newest batch stays in flight.  Round-2
// counters: 7240 cyc/K-tile wall vs 2048 cyc matrix work (MfmaUtil 31%) —
// the read windows sat wholly on the critical path between barrier pairs.
//
// Per-tile (BN=256; 4 phases, 8 MFMA of 32x32x16 each):
//   W0: read q0,B (12) | read-ahead q1 (4) | stage A23(t+1,other)
//       -> barrier -> lgkm(4) -> MFMA(0)
//   W1: read-ahead q2 | stage B01(t+2,this) -> barrier -> lgkm(4) -> MFMA(1)
//   W2: read-ahead q3 | stage B23(t+2,this) -> barrier -> lgkm(4) -> MFMA(2)
//   W3:               | stage A01(t+2,this) -> barrier -> lgkm(0) -> MFMA(3)
//   boundary: vmcnt(6) (tail 0) -> barrier                  [stages unchanged]
// Ledger (region last read >=1 barrier before its stage): q1 region staged W3
// (read-ahead at W0, 3 barrier-pairs earlier); q2/q3 regions staged at next
// tile's W0 (after boundary); B staged W1/W2, read at W0.  Boundary vmcnt
// unchanged: outstanding 14, t+1's 8 oldest must drain -> vmcnt(6).
//
// Per-tile (BN=128; 2 phases, 8 MFMA each): ALL reads at the boundary window
// (B,q0,q1 then read-ahead q2,q3; prior-tile boundary vmcnt(4) already
// guarantees every stripe of tile t, incl. A23(t), has landed):
//   WA: reads(12+8) | stage A23(t+1) -> barrier -> lgkm(8) -> MFMA(A: q0,q1)
//   WB:             | stage B01,A01(t+2) -> barrier -> lgkm(0) -> MFMA(B: q2,q3)
//   boundary: vmcnt(4) (tail 0) -> barrier
//
// LDS swizzle (0 measured conflict cycles): 16B chunk c of row r at
// c ^ (r&7) ^ ((r>>3)&3); global source pre-swizzled, LDS linear.
// C/D: col=lane&31, row=(reg&3)+8*(reg>>2)+4*(lane>>5).
// EPI: 0 = out_bf16 = acc*scale; 1 = out_f32 = acc+res;
//      2 = out_bf16 = gelu(acc+bias); 3 = out_f32 = acc+bias+res
// ============================================================================

#define STA(q, tk, bofs) async_ld16(srcA[q] + ((size_t)(tk) << 6), &As[(bofs) + ldsA[q]])
#define STB(j, tk, bofs) async_ld16(srcB[j] + ((size_t)(tk) << 6), &Bs[(bofs) + ldsB[j]])

#define RDQ(dst, Q)                                                         \
  _Pragma("unroll") for (int s = 0; s < 4; ++s)                             \
      dst[s] = *(const s8vec*)&As[aB + aoff + (Q) * 2048 + pc[s]];

#define SB0() __builtin_amdgcn_sched_barrier(0)

template <int BN, int EPI>
__global__ __launch_bounds__(512, 2) void gemm_nt8(
    const unsigned short* __restrict__ A, const unsigned short* __restrict__ B,
    float* __restrict__ outF, unsigned short* __restrict__ outB,
    const float* __restrict__ bias, const float* __restrict__ res,
    int M, int N, int K,
    long long bA, long long bB, long long bO, long long bR, float scale)
{
  static_assert(BN == 256 || BN == 128, "BN must be 256 or 128");
  constexpr int NB = BN / 64;      // B stage stripes per K-tile (4 or 2)
  constexpr int NF = BN / 128;     // N-frags per wave (2 or 1)
  constexpr int WN = BN / 4;       // wave N extent (64 or 32)
  constexpr int ABUF = 256 * 64;   // elements per A buffer (32 KiB)
  constexpr int BBUF = BN * 64;

  __shared__ __align__(16) unsigned short As[2 * ABUF];
  __shared__ __align__(16) unsigned short Bs[2 * BBUF];

  (void)M;
  const int tid = threadIdx.x;
  const int w = tid >> 6;          // wave 0..7
  const int l = tid & 63;

  // ---- T1: XCD-aware bijective remap (nwg % 8 == 0, gx/gy pow2) ----
  const unsigned gx = gridDim.x, gy = gridDim.y;
  unsigned lin = blockIdx.x + gx * (blockIdx.y + gy * blockIdx.z);
  const unsigned nwg = gx * gy * gridDim.z;
  lin = (lin & 7u) * (nwg >> 3) + (lin >> 3);
  const unsigned bx = lin & (gx - 1u);
  const unsigned tmp = lin >> __builtin_ctz(gx);
  const unsigned by = tmp & (gy - 1u);
  const unsigned bz = tmp >> __builtin_ctz(gy);

  const int z = (int)bz;
  A += (size_t)z * bA;
  B += (size_t)z * bB;
  const size_t tileM = (size_t)by * 256;
  const size_t tileN = (size_t)bx * BN;

  // ---- staging source pointers (global pre-swizzled, LDS linear) ----
  const int sub = w & 3, half = w >> 2;
  const unsigned short* srcA[4];
  int ldsA[4];
#pragma unroll
  for (int q = 0; q < 4; ++q) {
    const int rb = q * 32 + sub * 8 + half * 128;      // stripe q: rows {32q..}+{128+32q..}
    const int r = rb + (l >> 3);
    const int c = (l & 7) ^ (r & 7) ^ ((r >> 3) & 3);
    srcA[q] = A + (tileM + r) * (size_t)K + (c << 3);
    ldsA[q] = rb * 64;
  }
  const unsigned short* srcB[NB];
  int ldsB[NB];
#pragma unroll
  for (int j = 0; j < NB; ++j) {
    const int rb = j * 64 + w * 8;
    const int r = rb + (l >> 3);
    const int c = (l & 7) ^ (r & 7) ^ ((r >> 3) & 3);
    srcB[j] = B + (tileN + r) * (size_t)K + (c << 3);
    ldsB[j] = rb * 64;
  }

  // ---- compute-side fragment addressing ----
  const int wm = half;             // wave M origin / 128
  const int wn = sub;              // wave N origin / WN
  const int fr = l & 31;
  const int fq = l >> 5;
  const int swz = (l & 7) ^ ((l >> 3) & 3);            // = f(row) for row=base+fr, base%32==0
  int pc[4];
#pragma unroll
  for (int s = 0; s < 4; ++s) pc[s] = ((((s << 1) + fq) ^ swz) << 3);
  const int aoff = (wm * 128 + fr) * 64;
  int boff[NF];
#pragma unroll
  for (int nf = 0; nf < NF; ++nf) boff[nf] = (wn * WN + nf * 32 + fr) * 64;

  f32x16 acc[4][NF] = {};
  const int NT = K >> 6;           // K-tiles (>=16 and even at all call sites)

  if constexpr (BN == 256) {
    // ---- prologue: t0 full (oldest 8), then t1 B (4) + A-s0,s1 (2) ----
    STA(0, 0, 0); STA(1, 0, 0); STA(2, 0, 0); STA(3, 0, 0);
#pragma unroll
    for (int j = 0; j < 4; ++j) STB(j, 0, 0);
#pragma unroll
    for (int j = 0; j < 4; ++j) STB(j, 1, BBUF);
    STA(0, 1, ABUF); STA(1, 1, ABUF);
    asm volatile("s_waitcnt vmcnt(6)" ::: "memory");
    __builtin_amdgcn_s_barrier();

    auto tile = [&](int t, int bf) {
      const int aB = bf * ABUF, bBo = bf * BBUF, oaB = (bf ^ 1) * ABUF;
      const bool g1 = (t + 1 < NT), g2 = (t + 2 < NT);
      s8vec b[2][4];
      s8vec afA[4], afB[4];

      // -- W0: q0 + B (12 reads), then read-ahead q1; stage A23(t+1) --
      RDQ(afA, 0);
#pragma unroll
      for (int nf = 0; nf < 2; ++nf)
#pragma unroll
        for (int s = 0; s < 4; ++s)
          b[nf][s] = *(const s8vec*)&Bs[bBo + boff[nf] + pc[s]];
      SB0();                         // pin batch boundary: q0,B | q1
      RDQ(afB, 1);
      if (g1) { STA(2, t + 1, oaB); STA(3, t + 1, oaB); }
      SB0();
      __builtin_amdgcn_s_barrier();
      asm volatile("s_waitcnt lgkmcnt(4)" ::: "memory");   // q0,B done; q1 in flight
      SB0();
      __builtin_amdgcn_s_setprio(1);
#pragma unroll
      for (int s = 0; s < 4; ++s)
#pragma unroll
        for (int nf = 0; nf < 2; ++nf)
          acc[0][nf] = __builtin_amdgcn_mfma_f32_32x32x16_bf16(afA[s], b[nf][s], acc[0][nf], 0, 0, 0);
      __builtin_amdgcn_s_setprio(0);
      __builtin_amdgcn_s_barrier();

      // -- W1: read-ahead q2; stage B01(t+2); MFMA(1) on q1 --
      RDQ(afA, 2);
      if (g2) { STB(0, t + 2, bBo); STB(1, t + 2, bBo); }
      SB0();
      __builtin_amdgcn_s_barrier();
      asm volatile("s_waitcnt lgkmcnt(4)" ::: "memory");   // q1 done; q2 in flight
      SB0();
      __builtin_amdgcn_s_setprio(1);
#pragma unroll
      for (int s = 0; s < 4; ++s)
#pragma unroll
        for (int nf = 0; nf < 2; ++nf)
          acc[1][nf] = __builtin_amdgcn_mfma_f32_32x32x16_bf16(afB[s], b[nf][s], acc[1][nf], 0, 0, 0);
      __builtin_amdgcn_s_setprio(0);
      __builtin_amdgcn_s_barrier();

      // -- W2: read-ahead q3; stage B23(t+2); MFMA(2) on q2 --
      RDQ(afB, 3);
      if (g2) { STB(2, t + 2, bBo); STB(3, t + 2, bBo); }
      SB0();
      __builtin_amdgcn_s_barrier();
      asm volatile("s_waitcnt lgkmcnt(4)" ::: "memory");   // q2 done; q3 in flight
      SB0();
      __builtin_amdgcn_s_setprio(1);
#pragma unroll
      for (int s = 0; s < 4; ++s)
#pragma unroll
        for (int nf = 0; nf < 2; ++nf)
          acc[2][nf] = __builtin_amdgcn_mfma_f32_32x32x16_bf16(afA[s], b[nf][s], acc[2][nf], 0, 0, 0);
      __builtin_amdgcn_s_setprio(0);
      __builtin_amdgcn_s_barrier();

      // -- W3: no reads; stage A01(t+2); MFMA(3) on q3; boundary vmcnt --
      if (g2) { STA(0, t + 2, aB); STA(1, t + 2, aB); }
      SB0();
      __builtin_amdgcn_s_barrier();
      asm volatile("s_waitcnt lgkmcnt(0)" ::: "memory");   // q3 done
      SB0();
      __builtin_amdgcn_s_setprio(1);
#pragma unroll
      for (int s = 0; s < 4; ++s)
#pragma unroll
        for (int nf = 0; nf < 2; ++nf)
          acc[3][nf] = __builtin_amdgcn_mfma_f32_32x32x16_bf16(afB[s], b[nf][s], acc[3][nf], 0, 0, 0);
      __builtin_amdgcn_s_setprio(0);
      if (g2) asm volatile("s_waitcnt vmcnt(6)" ::: "memory");
      else    asm volatile("s_waitcnt vmcnt(0)" ::: "memory");
      __builtin_amdgcn_s_barrier();
    };

    for (int t = 0; t < NT; t += 2) { tile(t, 0); tile(t + 1, 1); }
  } else {
    // ---- prologue: t0 full (oldest 6), then t1 B (2) + A-s0,s1 (2) ----
    STA(0, 0, 0); STA(1, 0, 0); STA(2, 0, 0); STA(3, 0, 0);
    STB(0, 0, 0); STB(1, 0, 0);
    STB(0, 1, BBUF); STB(1, 1, BBUF);
    STA(0, 1, ABUF); STA(1, 1, ABUF);
    asm volatile("s_waitcnt vmcnt(4)" ::: "memory");
    __builtin_amdgcn_s_barrier();

    auto tile = [&](int t, int bf) {
      const int aB = bf * ABUF, bBo = bf * BBUF, oaB = (bf ^ 1) * ABUF;
      const bool g1 = (t + 1 < NT), g2 = (t + 2 < NT);
      s8vec b[4], a0[4], a1[4], a2[4], a3[4];

      // -- WA: read B,q0,q1 (12), then read-ahead q2,q3 (8); stage A23(t+1).
      //    Prior boundary vmcnt(4) guaranteed ALL stripes of tile t landed. --
#pragma unroll
      for (int s = 0; s < 4; ++s) {
        b[s]  = *(const s8vec*)&Bs[bBo + boff[0] + pc[s]];
        a0[s] = *(const s8vec*)&As[aB + aoff + 0 * 2048 + pc[s]];
        a1[s] = *(const s8vec*)&As[aB + aoff + 1 * 2048 + pc[s]];
      }
      SB0();                         // pin batch boundary: B,q0,q1 | q2,q3
      RDQ(a2, 2);
      RDQ(a3, 3);
      if (g1) { STA(2, t + 1, oaB); STA(3, t + 1, oaB); }
      SB0();
      __builtin_amdgcn_s_barrier();
      asm volatile("s_waitcnt lgkmcnt(8)" ::: "memory");   // B,q0,q1 done; q2,q3 in flight
      SB0();
      __builtin_amdgcn_s_setprio(1);
#pragma unroll
      for (int s = 0; s < 4; ++s) {
        acc[0][0] = __builtin_amdgcn_mfma_f32_32x32x16_bf16(a0[s], b[s], acc[0][0], 0, 0, 0);
        acc[1][0] = __builtin_amdgcn_mfma_f32_32x32x16_bf16(a1[s], b[s], acc[1][0], 0, 0, 0);
      }
      __builtin_amdgcn_s_setprio(0);
      __builtin_amdgcn_s_barrier();

      // -- WB: stage B01(t+2)+A01(t+2); MFMA(B) on q2,q3; boundary vmcnt --
      if (g2) { STB(0, t + 2, bBo); STB(1, t + 2, bBo); STA(0, t + 2, aB); STA(1, t + 2, aB); }
      SB0();
      __builtin_amdgcn_s_barrier();
      asm volatile("s_waitcnt lgkmcnt(0)" ::: "memory");   // q2,q3 done
      SB0();
      __builtin_amdgcn_s_setprio(1);
#pragma unroll
      for (int s = 0; s < 4; ++s) {
        acc[2][0] = __builtin_amdgcn_mfma_f32_32x32x16_bf16(a2[s], b[s], acc[2][0], 0, 0, 0);
        acc[3][0] = __builtin_amdgcn_mfma_f32_32x32x16_bf16(a3[s], b[s], acc[3][0], 0, 0, 0);
      }
      __builtin_amdgcn_s_setprio(0);
      if (g2) asm volatile("s_waitcnt vmcnt(4)" ::: "memory");
      else    asm volatile("s_waitcnt vmcnt(0)" ::: "memory");
      __builtin_amdgcn_s_barrier();
    };

    for (int t = 0; t < NT; t += 2) { tile(t, 0); tile(t + 1, 1); }
  }

  // ---- epilogue.  C/D: col = lane&31, row = (reg&3)+8*(reg>>2)+4*(lane>>5) ----
  float* oF = outF + (size_t)z * bO;
  unsigned short* oB = outB + (size_t)z * bO;
  const float* rs = res + (size_t)z * bR;

  float bcol[NF];
  if (EPI >= 2) {
#pragma unroll
    for (int nf = 0; nf < NF; ++nf) bcol[nf] = bias[tileN + wn * WN + nf * 32 + fr];
  }

#pragma unroll
  for (int mf = 0; mf < 4; ++mf) {
#pragma unroll
    for (int r = 0; r < 16; ++r) {
      const size_t row = tileM + wm * 128 + (mf << 5) + (r & 3) + ((r >> 2) << 3) + (fq << 2);
      const size_t rb = row * (size_t)N;
#pragma unroll
      for (int nf = 0; nf < NF; ++nf) {
        const size_t col = tileN + wn * WN + (nf << 5) + fr;
        const float v = acc[mf][nf][r];
        if (EPI == 0) {
          oB[rb + col] = f2bf(v * scale);
        } else if (EPI == 1) {
          oF[rb + col] = v + rs[rb + col];
        } else if (EPI == 2) {
          oB[rb + col] = f2bf(fast_gelu(v + bcol[nf]));
        } else {
          oF[rb + col] = v + bcol[nf] + rs[rb + col];
        }
      }
    }
  }
}

// ---------- LayerNorm over rows of 1024 fp32 -> bf16 ----------
__global__ __launch_bounds__(256) void ln_row(
    const float* __restrict__ x, const float* __restrict__ gamma,
    const float* __restrict__ beta, unsigned short* __restrict__ out)
{
  const int row = blockIdx.x;
  const float4* xr = (const float4*)(x + (size_t)row * 1024);
  const int tid = threadIdx.x;
  float4 v = xr[tid];
  float s = v.x + v.y + v.z + v.w;
  float q = v.x * v.x + v.y * v.y + v.z * v.z + v.w * v.w;
#pragma unroll
  for (int off = 32; off > 0; off >>= 1) {
    s += __shfl_down(s, off);
    q += __shfl_down(q, off);
  }
  __shared__ float rs_[4], rq_[4];
  const int w = tid >> 6, l = tid & 63;
  if (l == 0) { rs_[w] = s; rq_[w] = q; }
  __syncthreads();
  s = rs_[0] + rs_[1] + rs_[2] + rs_[3];
  q = rq_[0] + rq_[1] + rq_[2] + rq_[3];
  const float mu = s * (1.0f / 1024.0f);
  const float var = q * (1.0f / 1024.0f) - mu * mu;
  const float rstd = rsqrtf(var + 1e-5f);
  const float4 g = ((const float4*)gamma)[tid];
  const float4 b = ((const float4*)beta)[tid];
  us4 o;
  o.x = f2bf((v.x - mu) * rstd * g.x + b.x);
  o.y = f2bf((v.y - mu) * rstd * g.y + b.y);
  o.z = f2bf((v.z - mu) * rstd * g.z + b.z);
  o.w = f2bf((v.w - mu) * rstd * g.w + b.w);
  ((us4*)(out + (size_t)row * 1024))[tid] = o;
}

// ---------- softmax over rows of 2048 bf16 -> bf16 ----------
__global__ __launch_bounds__(256) void softmax_row(
    const unsigned short* __restrict__ sc, unsigned short* __restrict__ pr)
{
  const int row = blockIdx.x;
  const s8vec* s8 = (const s8vec*)(sc + (size_t)row * 2048);
  const int tid = threadIdx.x;
  s8vec a = s8[tid];                 // 8 bf16
  float x[8];
#pragma unroll
  for (int i = 0; i < 8; ++i) x[i] = bf2f((unsigned short)a[i]);
  float mx = x[0];
#pragma unroll
  for (int i = 1; i < 8; ++i) mx = fmaxf(mx, x[i]);
#pragma unroll
  for (int off = 32; off > 0; off >>= 1) mx = fmaxf(mx, __shfl_down(mx, off));
  __shared__ float red[4];
  const int w = tid >> 6, l = tid & 63;
  if (l == 0) red[w] = mx;
  __syncthreads();
  mx = fmaxf(fmaxf(red[0], red[1]), fmaxf(red[2], red[3]));
  __syncthreads();
  float e[8], s = 0.f;
#pragma unroll
  for (int i = 0; i < 8; ++i) { e[i] = __expf(x[i] - mx); s += e[i]; }
#pragma unroll
  for (int off = 32; off > 0; off >>= 1) s += __shfl_down(s, off);
  if (l == 0) red[w] = s;
  __syncthreads();
  s = red[0] + red[1] + red[2] + red[3];
  const float inv = 1.0f / s;
  s8vec o;
#pragma unroll
  for (int i = 0; i < 8; ++i) o[i] = (short)f2bf(e[i] * inv);
  ((s8vec*)(pr + (size_t)row * 2048))[tid] = o;
}

// ---------- transpose + convert to bf16: in[R,C] -> out[C,R] ----------
template <bool BF16IN>
__global__ __launch_bounds__(256) void transpose_conv(
    const void* __restrict__ in_, unsigned short* __restrict__ out,
    int R, int C, long long bIn, long long bOut)
{
  __shared__ float tile[32][33];
  const int z = blockIdx.z;
  const int tx = threadIdx.x, ty = threadIdx.y;   // block (32,8)
  const int c0 = blockIdx.x * 32, r0 = blockIdx.y * 32;
  if (BF16IN) {
    const unsigned short* in = (const unsigned short*)in_ + (size_t)z * bIn;
    for (int i = ty; i < 32; i += 8)
      tile[i][tx] = bf2f(in[(size_t)(r0 + i) * C + c0 + tx]);
  } else {
    const float* in = (const float*)in_ + (size_t)z * bIn;
    for (int i = ty; i < 32; i += 8)
      tile[i][tx] = in[(size_t)(r0 + i) * C + c0 + tx];
  }
  __syncthreads();
  unsigned short* o = out + (size_t)z * bOut;
  for (int i = ty; i < 32; i += 8)
    o[(size_t)(c0 + i) * R + r0 + tx] = f2bf(tile[tx][i]);
}

// ---------- launch ----------
extern "C" void kernel_launch(void* const* d_in, const int* in_sizes, int n_in,
                              void* d_out, int out_size, void* d_ws, size_t ws_size,
                              hipStream_t stream)
{
  (void)in_sizes; (void)n_in; (void)out_size; (void)ws_size;
  const float* src = (const float*)d_in[0];
  const float* g1  = (const float*)d_in[1];
  const float* be1 = (const float*)d_in[2];
  const float* g2  = (const float*)d_in[3];
  const float* be2 = (const float*)d_in[4];
  const float* w1  = (const float*)d_in[5];
  const float* b1  = (const float*)d_in[6];
  const float* w2  = (const float*)d_in[7];
  const float* b2  = (const float*)d_in[8];
  float* out = (float*)d_out;

  // workspace layout (bytes). Peak = 184,549,376.
  char* ws = (char*)d_ws;
  const size_t SZ_NORMX  = (size_t)8192 * 1024 * 2;     // 16 MiB
  const size_t SZ_SCORES = (size_t)4 * 2048 * 2048 * 4; // 64 MiB region (scores bf16 uses half; hbuf uses all)
  const size_t SZ_PROBS  = (size_t)4 * 2048 * 2048 * 2; // 32 MiB
  const size_t SZ_X      = (size_t)8192 * 1024 * 4;     // 32 MiB
  const size_t SZ_W1T    = (size_t)1024 * 4096 * 2;     // 8 MiB

  unsigned short* normx  = (unsigned short*)(ws);
  unsigned short* normxT = (unsigned short*)(ws + SZ_NORMX);
  unsigned short* scores = (unsigned short*)(ws + 2 * SZ_NORMX);
  unsigned short* probs  = (unsigned short*)(ws + 2 * SZ_NORMX + SZ_SCORES);
  float*          xbuf   = (float*)(ws + 2 * SZ_NORMX + SZ_SCORES + SZ_PROBS);
  unsigned short* w1t    = (unsigned short*)(ws + 2 * SZ_NORMX + SZ_SCORES + SZ_PROBS + SZ_X);
  unsigned short* w2t    = (unsigned short*)(ws + 2 * SZ_NORMX + SZ_SCORES + SZ_PROBS + SZ_X + SZ_W1T);
  unsigned short* normx2 = normx;                       // reuse (dead after attn)
  unsigned short* hbuf   = scores;                      // reuse (dead after softmax)

  const dim3 tb(32, 8);
  // weights fp32 -> bf16 transposed (every call; ws is re-poisoned)
  transpose_conv<false><<<dim3(128, 32, 1), tb, 0, stream>>>(w1, w1t, 1024, 4096, 0, 0);
  transpose_conv<false><<<dim3(32, 128, 1), tb, 0, stream>>>(w2, w2t, 4096, 1024, 0, 0);

  // LN1
  ln_row<<<8192, 256, 0, stream>>>(src, g1, be1, normx);
  // normx^T per batch (for PV as NT)
  transpose_conv<true><<<dim3(32, 64, 4), tb, 0, stream>>>(
      normx, normxT, 2048, 1024, (long long)2048 * 1024, (long long)1024 * 2048);

  // scores = bf16(normx . normx^T / 32)
  gemm_nt8<256, 0><<<dim3(8, 8, 4), 512, 0, stream>>>(
      normx, normx, nullptr, scores, nullptr, nullptr,
      2048, 2048, 1024,
      (long long)2048 * 1024, (long long)2048 * 1024, (long long)2048 * 2048, 0, 0.03125f);

  // softmax rows (bf16 in/out)
  softmax_row<<<8192, 256, 0, stream>>>(scores, probs);

  // x = probs . normx + src
  gemm_nt8<128, 1><<<dim3(8, 8, 4), 512, 0, stream>>>(
      probs, normxT, xbuf, nullptr, nullptr, src,
      2048, 1024, 2048,
      (long long)2048 * 2048, (long long)1024 * 2048, (long long)2048 * 1024,
      (long long)2048 * 1024, 1.0f);

  // LN2
  ln_row<<<8192, 256, 0, stream>>>(xbuf, g2, be2, normx2);

  // h = gelu(normx2 . w1 + b1)
  gemm_nt8<256, 2><<<dim3(16, 32, 1), 512, 0, stream>>>(
      normx2, w1t, nullptr, hbuf, b1, nullptr,
      8192, 4096, 1024, 0, 0, 0, 0, 1.0f);

  // out = h . w2 + b2 + x
  gemm_nt8<128, 3><<<dim3(8, 32, 1), 512, 0, stream>>>(
      hbuf, w2t, out, nullptr, b2, xbuf,
      8192, 1024, 4096, 0, 0, 0, 0, 1.0f);
}